// Round 4
// baseline (216.596 us; speedup 1.0000x reference)
//
#include <hip/hip_runtime.h>

// MultiheadAttention: bs=2, n_ctx=2048, width=1024, HEADS=16, head_dim=64, fp32 in/out.
// Pipeline: split/transpose converts -> bf16x3 QKV GEMM -> swapped-QK 32x32 flash attention -> bf16x3 proj GEMM.

using u16 = unsigned short;
typedef __attribute__((ext_vector_type(8))) short s16x8;    // 8 bf16 = 4 VGPR (MFMA A/B frag)
typedef __attribute__((ext_vector_type(4))) float f32x4;    // 16x16 MFMA C/D frag
typedef __attribute__((ext_vector_type(16))) float f32x16;  // 32x32 MFMA C/D frag

__device__ __forceinline__ u16 f2bf(float f) {
    unsigned x = __builtin_bit_cast(unsigned, f);
    x += 0x7fffu + ((x >> 16) & 1u);            // RNE
    return (u16)(x >> 16);
}
__device__ __forceinline__ float bf2f(u16 u) {
    return __builtin_bit_cast(float, ((unsigned)u) << 16);
}
// pack two f32 -> {lo: bf16(lo), hi: bf16(hi)} with RNE — same numerics as f2bf
// (round-3 post-mortem: v_cvt_pk_bf16_f32 operand/packing semantics gave a pairwise
//  kv swap, absmax 7e-4; this explicit pack is the round-2-verified path).
__device__ __forceinline__ unsigned pk2bf(float lo, float hi) {
    unsigned a = __builtin_bit_cast(unsigned, lo);
    unsigned b = __builtin_bit_cast(unsigned, hi);
    a += 0x7fffu + ((a >> 16) & 1u);
    b += 0x7fffu + ((b >> 16) & 1u);
    return (a >> 16) | (b & 0xffff0000u);
}

#define MFMA(a, b, c)   __builtin_amdgcn_mfma_f32_16x16x32_bf16((a), (b), (c), 0, 0, 0)
#define MFMA32(a, b, c) __builtin_amdgcn_mfma_f32_32x32x16_bf16((a), (b), (c), 0, 0, 0)

// ---------------- converts ----------------

__global__ __launch_bounds__(256) void convert_split(const float* __restrict__ in,
                                                     u16* __restrict__ H, u16* __restrict__ L, int n) {
    int i = (blockIdx.x * 256 + threadIdx.x) * 4;
    if (i >= n) return;
    float4 v = *(const float4*)(in + i);
    u16 h0 = f2bf(v.x), h1 = f2bf(v.y), h2 = f2bf(v.z), h3 = f2bf(v.w);
    ushort4 hh = { h0, h1, h2, h3 };
    ushort4 ll = { f2bf(v.x - bf2f(h0)), f2bf(v.y - bf2f(h1)), f2bf(v.z - bf2f(h2)), f2bf(v.w - bf2f(h3)) };
    *(ushort4*)(H + i) = hh;
    *(ushort4*)(L + i) = ll;
}

// W[K][N] fp32 -> WT[N][K] bf16 hi/lo.
__global__ __launch_bounds__(256) void transpose_split(const float* __restrict__ W,
                                                       u16* __restrict__ TH, u16* __restrict__ TL,
                                                       int K, int N) {
    __shared__ float st[32][33];
    int n0 = blockIdx.x * 32, k0 = blockIdx.y * 32;
    int c = threadIdx.x & 31, r8 = threadIdx.x >> 5;
#pragma unroll
    for (int i = 0; i < 4; ++i) {
        int r = r8 + i * 8;
        st[r][c] = W[(size_t)(k0 + r) * N + n0 + c];
    }
    __syncthreads();
#pragma unroll
    for (int i = 0; i < 4; ++i) {
        int r = r8 + i * 8;
        float v = st[c][r];
        u16 h = f2bf(v);
        TH[(size_t)(n0 + r) * K + k0 + c] = h;
        TL[(size_t)(n0 + r) * K + k0 + c] = f2bf(v - bf2f(h));
    }
}

// ---------------- bf16x3 GEMM (128x128 tile, BK=32, 4 waves) ----------------
// EPI 0: QKV epilogue -> Qs (scaled log2e/8) [bh][s][64], K [bh][s][64], Vp (sigma-permuted).
// EPI 1: proj epilogue -> fp32 out + bias.

template <int EPI>
__global__ __launch_bounds__(256, 2) void gemm_bf16x3(
    const u16* __restrict__ AH, const u16* __restrict__ AL,
    const u16* __restrict__ BTH, const u16* __restrict__ BTL,
    const float* __restrict__ bias,
    u16* __restrict__ Qs, u16* __restrict__ Kb, u16* __restrict__ Vp,
    float* __restrict__ Out) {
    const int K = 1024;
    __shared__ u16 sAh[128][40], sAl[128][40], sBh[128][40], sBl[128][40];

    int m0 = blockIdx.y * 128, n0 = blockIdx.x * 128;
    int tid = threadIdx.x, lane = tid & 63, wv = tid >> 6;
    int g = lane >> 4, c16 = lane & 15;
    int wm = wv >> 1, wn = wv & 1;

    f32x4 acc[4][4] = {};

    for (int kt = 0; kt < 32; ++kt) {
        int k0 = kt * 32;
        s16x8 ra[2], rla[2], rb[2], rlb[2];
#pragma unroll
        for (int i = 0; i < 2; ++i) {
            int cc = i * 256 + tid;
            int rr = cc >> 2, ko = (cc & 3) * 8;
            ra[i]  = *(const s16x8*)(AH  + (size_t)(m0 + rr) * K + k0 + ko);
            rla[i] = *(const s16x8*)(AL  + (size_t)(m0 + rr) * K + k0 + ko);
            rb[i]  = *(const s16x8*)(BTH + (size_t)(n0 + rr) * K + k0 + ko);
            rlb[i] = *(const s16x8*)(BTL + (size_t)(n0 + rr) * K + k0 + ko);
        }
        __syncthreads();
#pragma unroll
        for (int i = 0; i < 2; ++i) {
            int cc = i * 256 + tid;
            int rr = cc >> 2, ko = (cc & 3) * 8;
            *(s16x8*)&sAh[rr][ko] = ra[i];
            *(s16x8*)&sAl[rr][ko] = rla[i];
            *(s16x8*)&sBh[rr][ko] = rb[i];
            *(s16x8*)&sBl[rr][ko] = rlb[i];
        }
        __syncthreads();

        s16x8 ah[4], al[4], bh[4], bl[4];
#pragma unroll
        for (int mi = 0; mi < 4; ++mi) {
            ah[mi] = *(const s16x8*)&sAh[wm * 64 + mi * 16 + c16][g * 8];
            al[mi] = *(const s16x8*)&sAl[wm * 64 + mi * 16 + c16][g * 8];
        }
#pragma unroll
        for (int ni = 0; ni < 4; ++ni) {
            bh[ni] = *(const s16x8*)&sBh[wn * 64 + ni * 16 + c16][g * 8];
            bl[ni] = *(const s16x8*)&sBl[wn * 64 + ni * 16 + c16][g * 8];
        }
#pragma unroll
        for (int mi = 0; mi < 4; ++mi)
#pragma unroll
            for (int ni = 0; ni < 4; ++ni) {
                f32x4 c = acc[mi][ni];
                c = MFMA(ah[mi], bh[ni], c);
                c = MFMA(al[mi], bh[ni], c);
                c = MFMA(ah[mi], bl[ni], c);
                acc[mi][ni] = c;
            }
    }

    // C/D layout: col = lane&15, row = 4*(lane>>4)+reg
#pragma unroll
    for (int ni = 0; ni < 4; ++ni) {
        int col = n0 + wn * 64 + ni * 16 + c16;
        float bs = bias[col];
        if (EPI == 0) {
            int h = col / 192;
            int rm = col - h * 192;
#pragma unroll
            for (int mi = 0; mi < 4; ++mi)
#pragma unroll
                for (int r = 0; r < 4; ++r) {
                    int row = m0 + wm * 64 + mi * 16 + 4 * g + r;
                    int b = row >> 11, s = row & 2047;
                    int bh16 = b * 16 + h;
                    float val = acc[mi][ni][r] + bs;
                    if (rm < 64)
                        // 1/8 softmax scale folded with log2(e) so attn can use exp2
                        Qs[(((size_t)bh16 * 2048 + s) << 6) + rm] = f2bf(val * 0.18033688011112042f);
                    else if (rm < 128)
                        Kb[(((size_t)bh16 * 2048 + s) << 6) + rm - 64] = f2bf(val);
                    else {
                        // sigma-permuted V: Vp[bh][s/16][d][m], kv = 16*(s/16)+sigma(m),
                        // sigma(m) = (m&3) + 8*((m>>2)&1) + 4*(m>>3)
                        int d = rm - 128;
                        int kg = s >> 4, k16 = s & 15;
                        int mm = (k16 & 3) | (((k16 >> 3) & 1) << 2) | (((k16 >> 2) & 1) << 3);
                        Vp[(((size_t)bh16 * 128 + kg) * 64 + d) * 16 + mm] = f2bf(val);
                    }
                }
        } else {
#pragma unroll
            for (int mi = 0; mi < 4; ++mi)
#pragma unroll
                for (int r = 0; r < 4; ++r) {
                    int row = m0 + wm * 64 + mi * 16 + 4 * g + r;
                    Out[(size_t)row * 1024 + col] = acc[mi][ni][r] + bs;
                }
        }
    }
}

// ---------------- flash attention, swapped-QK 32x32 MFMA, no LDS ----------------
// S = mfma32(A=K, B=Q): lane holds q = lane&31, s[r] = S[kv0 + crow(r,h)][q],
// crow(r,h) = (r&3) + 8*(r>>2) + 4*h, h = lane>>5.  Softmax in-lane + 1 shfl_xor(32).
// 64 kv per softmax pass (two 32x32 S tiles). Q pre-scaled by log2e/8 -> exp2.
// PV: A-frag elem e = exp'd s[e] / s[8+e]; V sigma-permuted to match kv ordering.
__global__ __launch_bounds__(256, 2) void attn_fwd(
    const u16* __restrict__ Qs, const u16* __restrict__ Kb, const u16* __restrict__ Vp,
    u16* __restrict__ OH, u16* __restrict__ OL) {
    int id = blockIdx.x;
    int xcd = id & 7, li = id >> 3;          // 4 heads per XCD -> K/V (2MB) stays L2-resident
    int bh = xcd * 4 + (li >> 4);
    int qb = li & 15;
    int tid = threadIdx.x, w = tid >> 6, lane = tid & 63;
    int l31 = lane & 31, h = lane >> 5;
    int q0 = (qb * 4 + w) * 32;

    size_t base = (size_t)bh * 2048 * 64;
    size_t vbase = (size_t)bh * 131072;       // 128*64*16

    const u16* qp = Qs + base + (size_t)(q0 + l31) * 64 + 8 * h;
    s16x8 qf[4];
#pragma unroll
    for (int c = 0; c < 4; ++c) qf[c] = *(const s16x8*)(qp + 16 * c);

    const u16* kp = Kb + base + (size_t)l31 * 64 + 8 * h;
    const u16* vb = Vp + vbase + (size_t)l31 * 16 + 8 * h;

    f32x16 o0 = {}, o1 = {};
    float m = -1e30f, ls = 0.f;

    s16x8 kA[8], kB[8];
#pragma unroll
    for (int i = 0; i < 8; ++i)
        kA[i] = *(const s16x8*)(kp + (i >> 2) * 2048 + (i & 3) * 16);

    auto step = [&](s16x8 (&cur)[8], s16x8 (&nxt)[8], int j) {
        // V frags for this 64-kv chunk: v[b*4 + hf*2 + n]
        const u16* vp = vb + (size_t)j * 4096;
        s16x8 v[8];
#pragma unroll
        for (int b = 0; b < 2; ++b)
#pragma unroll
            for (int hf = 0; hf < 2; ++hf)
#pragma unroll
                for (int n = 0; n < 2; ++n)
                    v[b * 4 + hf * 2 + n] = *(const s16x8*)(vp + b * 2048 + hf * 1024 + n * 512);

        f32x16 s0 = {}, s1 = {};
        s0 = MFMA32(cur[0], qf[0], s0);
        s0 = MFMA32(cur[1], qf[1], s0);
        s0 = MFMA32(cur[2], qf[2], s0);
        s0 = MFMA32(cur[3], qf[3], s0);
        s1 = MFMA32(cur[4], qf[0], s1);
        s1 = MFMA32(cur[5], qf[1], s1);
        s1 = MFMA32(cur[6], qf[2], s1);
        s1 = MFMA32(cur[7], qf[3], s1);

        // prefetch next K chunk
        int jn = (j + 1) & 31;
        const u16* kpn = kp + (size_t)jn * 4096;
#pragma unroll
        for (int i = 0; i < 8; ++i)
            nxt[i] = *(const s16x8*)(kpn + (i >> 2) * 2048 + (i & 3) * 16);

        // max over 32 values: 4 chains + combine + cross-half
        float t0 = fmaxf(s0[0], s1[0]), t1 = fmaxf(s0[1], s1[1]);
        float t2 = fmaxf(s0[2], s1[2]), t3 = fmaxf(s0[3], s1[3]);
#pragma unroll
        for (int r = 4; r < 16; r += 4) {
            t0 = fmaxf(t0, fmaxf(s0[r], s1[r]));
            t1 = fmaxf(t1, fmaxf(s0[r + 1], s1[r + 1]));
            t2 = fmaxf(t2, fmaxf(s0[r + 2], s1[r + 2]));
            t3 = fmaxf(t3, fmaxf(s0[r + 3], s1[r + 3]));
        }
        float pmax = fmaxf(fmaxf(t0, t1), fmaxf(t2, t3));
        pmax = fmaxf(pmax, __shfl_xor(pmax, 32));

        if (!__all(pmax <= m + 8.f)) {          // defer-max (T13), log2 units
            float mn = fmaxf(m, pmax);
            float f = __builtin_amdgcn_exp2f(m - mn);
            m = mn;
            ls *= f;
#pragma unroll
            for (int r = 0; r < 16; ++r) {
                float fb = __shfl(f, (r & 3) + 8 * (r >> 2) + 4 * h);
                o0[r] *= fb;
                o1[r] *= fb;
            }
        }

        float a0 = 0.f, a1 = 0.f, a2 = 0.f, a3 = 0.f;
#pragma unroll
        for (int r = 0; r < 16; r += 4) {
            s0[r]     = __builtin_amdgcn_exp2f(s0[r] - m);     a0 += s0[r];
            s0[r + 1] = __builtin_amdgcn_exp2f(s0[r + 1] - m); a1 += s0[r + 1];
            s0[r + 2] = __builtin_amdgcn_exp2f(s0[r + 2] - m); a2 += s0[r + 2];
            s0[r + 3] = __builtin_amdgcn_exp2f(s0[r + 3] - m); a3 += s0[r + 3];
            s1[r]     = __builtin_amdgcn_exp2f(s1[r] - m);     a0 += s1[r];
            s1[r + 1] = __builtin_amdgcn_exp2f(s1[r + 1] - m); a1 += s1[r + 1];
            s1[r + 2] = __builtin_amdgcn_exp2f(s1[r + 2] - m); a2 += s1[r + 2];
            s1[r + 3] = __builtin_amdgcn_exp2f(s1[r + 3] - m); a3 += s1[r + 3];
        }
        float sm = (a0 + a1) + (a2 + a3);
        sm += __shfl_xor(sm, 32);
        ls += sm;

        // pack P into PV A-frags (explicit RNE pack — element mapping identical to round 2)
        union { s16x8 v8; unsigned u[4]; } p00, p01, p10, p11;
#pragma unroll
        for (int k = 0; k < 4; ++k) {
            p00.u[k] = pk2bf(s0[2 * k], s0[2 * k + 1]);
            p01.u[k] = pk2bf(s0[8 + 2 * k], s0[9 + 2 * k]);
            p10.u[k] = pk2bf(s1[2 * k], s1[2 * k + 1]);
            p11.u[k] = pk2bf(s1[8 + 2 * k], s1[9 + 2 * k]);
        }

        o0 = MFMA32(p00.v8, v[0], o0);
        o1 = MFMA32(p00.v8, v[1], o1);
        o0 = MFMA32(p01.v8, v[2], o0);
        o1 = MFMA32(p01.v8, v[3], o1);
        o0 = MFMA32(p10.v8, v[4], o0);
        o1 = MFMA32(p10.v8, v[5], o1);
        o0 = MFMA32(p11.v8, v[6], o0);
        o1 = MFMA32(p11.v8, v[7], o1);
    };

    for (int j = 0; j < 32; j += 2) {
        step(kA, kB, j);
        step(kB, kA, j + 1);
    }

    int b = bh >> 4, hh = bh & 15;
    float inv = 1.0f / ls;
#pragma unroll
    for (int r = 0; r < 16; ++r) {
        int cr = (r & 3) + 8 * (r >> 2) + 4 * h;
        float fb = __shfl(inv, cr);
        int row = q0 + cr;
        size_t idx = ((size_t)(b * 2048 + row)) * 1024 + hh * 64 + l31;
        float v0 = o0[r] * fb, v1 = o1[r] * fb;
        u16 h0 = f2bf(v0);
        OH[idx] = h0;
        OL[idx] = f2bf(v0 - bf2f(h0));
        u16 h1 = f2bf(v1);
        OH[idx + 32] = h1;
        OL[idx + 32] = f2bf(v1 - bf2f(h1));
    }
}

// ---------------- launch ----------------

extern "C" void kernel_launch(void* const* d_in, const int* in_sizes, int n_in,
                              void* d_out, int out_size, void* d_ws, size_t ws_size,
                              hipStream_t stream) {
    const float* x     = (const float*)d_in[0];
    const float* Wqkv  = (const float*)d_in[1];
    const float* bqkv  = (const float*)d_in[2];
    const float* Wproj = (const float*)d_in[3];
    const float* bproj = (const float*)d_in[4];
    float* out = (float*)d_out;

    char* w = (char*)d_ws;
    const size_t SZ_X  = (size_t)4096 * 1024 * 2;  // 8 MiB (bf16)
    const size_t SZ_WQ = (size_t)3072 * 1024 * 2;
    const size_t SZ_WP = (size_t)1024 * 1024 * 2;
    u16* XH  = (u16*)w; w += SZ_X;
    u16* XL  = (u16*)w; w += SZ_X;
    u16* WQH = (u16*)w; w += SZ_WQ;
    u16* WQL = (u16*)w; w += SZ_WQ;
    u16* WPH = (u16*)w; w += SZ_WP;
    u16* WPL = (u16*)w; w += SZ_WP;
    u16* Q_s = (u16*)w; w += SZ_X;                  // [bh][s][64] scaled by log2e/8
    u16* K_b = (u16*)w; w += SZ_X;                  // [bh][s][64]
    u16* V_p = (u16*)w; w += SZ_X;                  // [bh][s/16][64][16] sigma-permuted
    u16* OHp = (u16*)w; w += SZ_X;                  // attn out hi [4096][1024]
    u16* OLp = (u16*)w; w += SZ_X;                  // attn out lo

    convert_split<<<4096, 256, 0, stream>>>(x, XH, XL, 4096 * 1024);
    transpose_split<<<dim3(96, 32), 256, 0, stream>>>(Wqkv, WQH, WQL, 1024, 3072);
    transpose_split<<<dim3(32, 32), 256, 0, stream>>>(Wproj, WPH, WPL, 1024, 1024);
    gemm_bf16x3<0><<<dim3(24, 32), 256, 0, stream>>>(XH, XL, WQH, WQL, bqkv, Q_s, K_b, V_p, nullptr);
    attn_fwd<<<512, 256, 0, stream>>>(Q_s, K_b, V_p, OHp, OLp);
    gemm_bf16x3<1><<<dim3(8, 32), 256, 0, stream>>>(OHp, OLp, WPH, WPL, bproj, nullptr, nullptr, nullptr, out);
}